// Round 1
// baseline (1156.724 us; speedup 1.0000x reference)
//
#include <hip/hip_runtime.h>
#include <math.h>

#define HID 64
#define HEADS 4
#define GR 64
#define NEG 0.2f

__device__ __forceinline__ float lrelu(float v){ return v > 0.f ? v : NEG * v; }
__device__ __forceinline__ float elu_(float v){ return v > 0.f ? v : expm1f(v); }

// deg=1 (self-loop), zero pooled sums/counts  (must run EVERY call: harness
// does not re-poison ws between timed replays)
__global__ void k_init(int* deg, float* sums, int* counts, int N){
    int i = blockIdx.x * blockDim.x + threadIdx.x;
    if (i < N) deg[i] = 1;
    if (i < GR * HID) sums[i] = 0.f;
    if (i < GR) counts[i] = 0;
}

__global__ void k_hist(const int* __restrict__ dst, int E, int* deg){
    int i = blockIdx.x * blockDim.x + threadIdx.x;
    if (i < E) atomicAdd(&deg[dst[i]], 1);
}

// block-level exclusive scan (chunk = 1024)
__global__ void k_scan1(const int* __restrict__ deg, int N, int* offs, int* bsum){
    __shared__ int sh[1024];
    int i = blockIdx.x * 1024 + threadIdx.x;
    int v = (i < N) ? deg[i] : 0;
    sh[threadIdx.x] = v;
    __syncthreads();
    for (int off = 1; off < 1024; off <<= 1){
        int t = (threadIdx.x >= off) ? sh[threadIdx.x - off] : 0;
        __syncthreads();
        sh[threadIdx.x] += t;
        __syncthreads();
    }
    if (i < N) offs[i] = sh[threadIdx.x] - v;      // exclusive within chunk
    if (threadIdx.x == 1023) bsum[blockIdx.x] = sh[1023];
}

__global__ void k_scan2(int* bsum, int nb){
    if (threadIdx.x == 0 && blockIdx.x == 0){
        int run = 0;
        for (int j = 0; j < nb; j++){ int t = bsum[j]; bsum[j] = run; run += t; }
    }
}

__global__ void k_scan3(int* offs, const int* __restrict__ bsum, int* cursor, int N, int Et){
    int i = blockIdx.x * 1024 + threadIdx.x;
    if (i < N){
        int o = offs[i] + bsum[blockIdx.x];
        offs[i] = o;
        cursor[i] = o;
    }
    if (i == 0) offs[N] = Et;
}

// CSR fill: edges + implicit self-loops (e>=E -> src=dst=e-E)
__global__ void k_fill(const int* __restrict__ src, const int* __restrict__ dst,
                       int E, int Et, int* cursor, int* ssrc){
    int i = blockIdx.x * blockDim.x + threadIdx.x;
    if (i >= Et) return;
    int s, d;
    if (i < E){ s = src[i]; d = dst[i]; } else { s = d = i - E; }
    int pos = atomicAdd(&cursor[d], 1);
    ssrc[pos] = s;
}

// xh1 = x @ W1  (F_in=2!), a_src1/a_dst1 per head. wave per node, lane = channel.
__global__ void k_node1(const float* __restrict__ x, const float* __restrict__ W1,
                        const float* __restrict__ asw, const float* __restrict__ adw,
                        int N, float* xh, float* asrc, float* adst){
    int wave = threadIdx.x >> 6, lane = threadIdx.x & 63;
    int n = blockIdx.x * 4 + wave;
    if (n >= N) return;
    float x0 = x[n * 2], x1 = x[n * 2 + 1];
    float ps[HEADS], pd[HEADS];
#pragma unroll
    for (int h = 0; h < HEADS; h++){
        int j = h * HID + lane;
        float v = x0 * W1[j] + x1 * W1[HEADS * HID + j];
        xh[n * (HEADS * HID) + j] = v;
        ps[h] = v * asw[j];
        pd[h] = v * adw[j];
    }
#pragma unroll
    for (int off = 32; off; off >>= 1){
#pragma unroll
        for (int h = 0; h < HEADS; h++){
            ps[h] += __shfl_xor(ps[h], off, 64);
            pd[h] += __shfl_xor(pd[h], off, 64);
        }
    }
    if (lane == 0){
#pragma unroll
        for (int h = 0; h < HEADS; h++){
            asrc[n * HEADS + h] = ps[h];
            adst[n * HEADS + h] = pd[h];
        }
    }
}

// layer-1 aggregation: wave per dst node; unnormalized weighted sum + denom,
// divide at end (== softmax result). No atomics.
__global__ void k_agg1(const float* __restrict__ xh, const float* __restrict__ asrc,
                       const float* __restrict__ adst, const int* __restrict__ offs,
                       const int* __restrict__ ssrc, const float* __restrict__ b1,
                       int N, float* __restrict__ h1){
    int wave = threadIdx.x >> 6, lane = threadIdx.x & 63;
    int n = blockIdx.x * 4 + wave;
    if (n >= N) return;
    float4 ad = *(const float4*)(adst + n * 4);
    float a0 = 0.f, a1 = 0.f, a2 = 0.f, a3 = 0.f;
    float d0 = 0.f, d1 = 0.f, d2 = 0.f, d3 = 0.f;
    int beg = offs[n], end = offs[n + 1];
    for (int j = beg; j < end; j++){
        int s = ssrc[j];
        float4 as = *(const float4*)(asrc + s * 4);
        float w0 = expf(lrelu(as.x + ad.x));
        float w1 = expf(lrelu(as.y + ad.y));
        float w2 = expf(lrelu(as.z + ad.z));
        float w3 = expf(lrelu(as.w + ad.w));
        const float* row = xh + (size_t)s * 256;
        a0 += w0 * row[lane];
        a1 += w1 * row[64 + lane];
        a2 += w2 * row[128 + lane];
        a3 += w3 * row[192 + lane];
        d0 += w0; d1 += w1; d2 += w2; d3 += w3;
    }
    size_t base = (size_t)n * 256;
    h1[base + lane]        = elu_(a0 / d0 + b1[lane]);
    h1[base + 64 + lane]   = elu_(a1 / d1 + b1[64 + lane]);
    h1[base + 128 + lane]  = elu_(a2 / d2 + b1[128 + lane]);
    h1[base + 192 + lane]  = elu_(a3 / d3 + b1[192 + lane]);
}

// xh2 = h1 @ W2 ([N,256]x[256,64]) + a_src2/a_dst2. wave per row, lane = out col.
__global__ void k_node2(const float* __restrict__ h1, const float* __restrict__ W2,
                        const float* __restrict__ asw, const float* __restrict__ adw,
                        int N, float* xh2, float* asrc, float* adst){
    int wave = threadIdx.x >> 6, lane = threadIdx.x & 63;
    int n = blockIdx.x * 4 + wave;
    if (n >= N) return;
    const float4* row4 = (const float4*)(h1 + (size_t)n * 256);
    float acc = 0.f;
#pragma unroll 4
    for (int k4 = 0; k4 < 64; k4++){
        float4 hv = row4[k4];
        int k = k4 * 4;
        acc += hv.x * W2[(k    ) * 64 + lane];
        acc += hv.y * W2[(k + 1) * 64 + lane];
        acc += hv.z * W2[(k + 2) * 64 + lane];
        acc += hv.w * W2[(k + 3) * 64 + lane];
    }
    xh2[(size_t)n * 64 + lane] = acc;
    float ps = acc * asw[lane], pd = acc * adw[lane];
#pragma unroll
    for (int off = 32; off; off >>= 1){
        ps += __shfl_xor(ps, off, 64);
        pd += __shfl_xor(pd, off, 64);
    }
    if (lane == 0){ asrc[n] = ps; adst[n] = pd; }
}

__global__ void k_agg2(const float* __restrict__ xh2, const float* __restrict__ asrc,
                       const float* __restrict__ adst, const int* __restrict__ offs,
                       const int* __restrict__ ssrc, const float* __restrict__ b2,
                       int N, float* __restrict__ h2){
    int wave = threadIdx.x >> 6, lane = threadIdx.x & 63;
    int n = blockIdx.x * 4 + wave;
    if (n >= N) return;
    float ad = adst[n];
    float acc = 0.f, den = 0.f;
    int beg = offs[n], end = offs[n + 1];
    for (int j = beg; j < end; j++){
        int s = ssrc[j];
        float w = expf(lrelu(asrc[s] + ad));
        acc += w * xh2[(size_t)s * 64 + lane];
        den += w;
    }
    h2[(size_t)n * 64 + lane] = elu_(acc / den + b2[lane]);
}

// global mean pool: batch is SORTED -> per-block register run-accumulation,
// flush via atomicAdd only on graph-id change / chunk end.
__global__ void k_pool(const float* __restrict__ h2, const int* __restrict__ batch,
                       int N, float* sums, int* counts){
    int lane = threadIdx.x & 63;   // blockDim = 64
    int chunk = (N + gridDim.x - 1) / gridDim.x;
    int beg = blockIdx.x * chunk;
    int end = min(beg + chunk, N);
    if (beg >= end) return;
    float acc = 0.f; int cnt = 0; int cur = batch[beg];
    for (int n = beg; n < end; n++){
        int g = batch[n];
        if (g != cur){
            atomicAdd(&sums[cur * HID + lane], acc);
            if (lane == 0) atomicAdd(&counts[cur], cnt);
            acc = 0.f; cnt = 0; cur = g;
        }
        acc += h2[(size_t)n * HID + lane];
        cnt++;
    }
    atomicAdd(&sums[cur * HID + lane], acc);
    if (lane == 0) atomicAdd(&counts[cur], cnt);
}

__global__ void k_final(const float* __restrict__ sums, const int* __restrict__ counts,
                        const float* __restrict__ Wl, const float* __restrict__ bl,
                        float* out){
    int t = threadIdx.x;
    if (t >= GR * 2) return;
    int g = t >> 1, task = t & 1;
    float c = (float)max(counts[g], 1);
    float acc = 0.f;
#pragma unroll
    for (int k = 0; k < HID; k++)
        acc += (sums[g * HID + k] / c) * Wl[k * 2 + task];
    out[t] = acc + bl[task];
}

extern "C" void kernel_launch(void* const* d_in, const int* in_sizes, int n_in,
                              void* d_out, int out_size, void* d_ws, size_t ws_size,
                              hipStream_t stream) {
    const float* x    = (const float*)d_in[0];
    const int*   ei   = (const int*)  d_in[1];
    const int*   batch= (const int*)  d_in[2];
    const float* W1   = (const float*)d_in[3];
    const float* as1  = (const float*)d_in[4];
    const float* ad1  = (const float*)d_in[5];
    const float* b1   = (const float*)d_in[6];
    const float* W2   = (const float*)d_in[7];
    const float* as2  = (const float*)d_in[8];
    const float* ad2  = (const float*)d_in[9];
    const float* b2   = (const float*)d_in[10];
    const float* Wl   = (const float*)d_in[11];
    const float* bl   = (const float*)d_in[12];
    float* out = (float*)d_out;

    int N  = in_sizes[0] / 2;      // x is [N,2]
    int E  = in_sizes[1] / 2;      // edge_index is [2,E]
    int Et = E + N;                // + self-loops
    const int* srcp = ei;
    const int* dstp = ei + E;

    // workspace carve (256B aligned); big buffers aliased across phases
    char* p = (char*)d_ws;
    auto alloc = [&](size_t bytes)->char* {
        char* r = p; p += (bytes + 255) & ~(size_t)255; return r;
    };
    int*   deg    = (int*)  alloc((size_t)N * 4);
    int*   offs   = (int*)  alloc((size_t)(N + 1) * 4);
    int*   cursor = (int*)  alloc((size_t)N * 4);
    int*   bsum   = (int*)  alloc(1024 * 4);
    int*   ssrc   = (int*)  alloc((size_t)Et * 4);
    float* asrc1  = (float*)alloc((size_t)N * HEADS * 4);
    float* adst1  = (float*)alloc((size_t)N * HEADS * 4);
    float* asrc2  = (float*)alloc((size_t)N * 4);
    float* adst2  = (float*)alloc((size_t)N * 4);
    float* sums   = (float*)alloc((size_t)GR * HID * 4);
    int*   counts = (int*)  alloc((size_t)GR * 4);
    float* bigA   = (float*)alloc((size_t)N * 256 * 4);  // xh1, later xh2
    float* bigB   = (float*)alloc((size_t)N * 256 * 4);  // h1,  later h2
    float* xh1 = bigA;  float* h1 = bigB;
    float* xh2 = bigA;  float* h2 = bigB;

    int nb1024 = (N + 1023) / 1024;
    int nwg4   = (N + 3) / 4;

    k_init <<<(N + 255) / 256, 256, 0, stream>>>(deg, sums, counts, N);
    k_hist <<<(E + 255) / 256, 256, 0, stream>>>(dstp, E, deg);
    k_scan1<<<nb1024, 1024, 0, stream>>>(deg, N, offs, bsum);
    k_scan2<<<1, 64, 0, stream>>>(bsum, nb1024);
    k_scan3<<<nb1024, 1024, 0, stream>>>(offs, bsum, cursor, N, Et);
    k_fill <<<(Et + 255) / 256, 256, 0, stream>>>(srcp, dstp, E, Et, cursor, ssrc);

    k_node1<<<nwg4, 256, 0, stream>>>(x, W1, as1, ad1, N, xh1, asrc1, adst1);
    k_agg1 <<<nwg4, 256, 0, stream>>>(xh1, asrc1, adst1, offs, ssrc, b1, N, h1);
    k_node2<<<nwg4, 256, 0, stream>>>(h1, W2, as2, ad2, N, xh2, asrc2, adst2);
    k_agg2 <<<nwg4, 256, 0, stream>>>(xh2, asrc2, adst2, offs, ssrc, b2, N, h2);

    k_pool <<<512, 64, 0, stream>>>(h2, batch, N, sums, counts);
    k_final<<<1, 128, 0, stream>>>(sums, counts, Wl, bl, out);
}

// Round 2
// 709.899 us; speedup vs baseline: 1.6294x; 1.6294x over previous
//
#include <hip/hip_runtime.h>
#include <math.h>

#define HID 64
#define HEADS 4
#define GR 64
#define NEG 0.2f

__device__ __forceinline__ float lrelu(float v){ return v > 0.f ? v : NEG * v; }
__device__ __forceinline__ float elu_(float v){ return v > 0.f ? v : expm1f(v); }

// deg=1 (self-loop), zero pooled sums/counts  (must run EVERY call: harness
// does not re-poison ws between timed replays)
__global__ void k_init(int* deg, float* sums, int* counts, int N){
    int i = blockIdx.x * blockDim.x + threadIdx.x;
    if (i < N) deg[i] = 1;
    if (i < GR * HID) sums[i] = 0.f;
    if (i < GR) counts[i] = 0;
}

__global__ void k_hist(const int* __restrict__ dst, int E, int* deg){
    int i = blockIdx.x * blockDim.x + threadIdx.x;
    if (i < E) atomicAdd(&deg[dst[i]], 1);
}

__global__ void k_scan1(const int* __restrict__ deg, int N, int* offs, int* bsum){
    __shared__ int sh[1024];
    int i = blockIdx.x * 1024 + threadIdx.x;
    int v = (i < N) ? deg[i] : 0;
    sh[threadIdx.x] = v;
    __syncthreads();
    for (int off = 1; off < 1024; off <<= 1){
        int t = (threadIdx.x >= off) ? sh[threadIdx.x - off] : 0;
        __syncthreads();
        sh[threadIdx.x] += t;
        __syncthreads();
    }
    if (i < N) offs[i] = sh[threadIdx.x] - v;
    if (threadIdx.x == 1023) bsum[blockIdx.x] = sh[1023];
}

__global__ void k_scan2(int* bsum, int nb){
    if (threadIdx.x == 0 && blockIdx.x == 0){
        int run = 0;
        for (int j = 0; j < nb; j++){ int t = bsum[j]; bsum[j] = run; run += t; }
    }
}

__global__ void k_scan3(int* offs, const int* __restrict__ bsum, int* cursor, int N, int Et){
    int i = blockIdx.x * 1024 + threadIdx.x;
    if (i < N){
        int o = offs[i] + bsum[blockIdx.x];
        offs[i] = o;
        cursor[i] = o;
    }
    if (i == 0) offs[N] = Et;
}

__global__ void k_fill(const int* __restrict__ src, const int* __restrict__ dst,
                       int E, int Et, int* cursor, int* ssrc){
    int i = blockIdx.x * blockDim.x + threadIdx.x;
    if (i >= Et) return;
    int s, d;
    if (i < E){ s = src[i]; d = dst[i]; } else { s = d = i - E; }
    int pos = atomicAdd(&cursor[d], 1);
    ssrc[pos] = s;
}

// attention-projection constants: cs0[h]=sum_c W1[0,h*64+c]*att_src[h,c] etc.
// cvec layout: [cs0(4), cs1(4), cd0(4), cd1(4)]
__global__ void k_const(const float* __restrict__ W1, const float* __restrict__ as1,
                        const float* __restrict__ ad1, float* cvec){
    int lane = threadIdx.x;      // 64 threads
    float v[4];
#pragma unroll
    for (int h = 0; h < HEADS; h++){
        int j = h * HID + lane;
        float s0 = W1[j]       * as1[j];
        float s1 = W1[256 + j] * as1[j];
        float d0 = W1[j]       * ad1[j];
        float d1 = W1[256 + j] * ad1[j];
#pragma unroll
        for (int off = 32; off; off >>= 1){
            s0 += __shfl_xor(s0, off, 64);
            s1 += __shfl_xor(s1, off, 64);
            d0 += __shfl_xor(d0, off, 64);
            d1 += __shfl_xor(d1, off, 64);
        }
        if (lane == 0){
            cvec[h] = s0; cvec[4 + h] = s1; cvec[8 + h] = d0; cvec[12 + h] = d1;
        }
        (void)v;
    }
}

// layer-1 aggregation via rank-2 trick: thread per dst node, gather only x[src]
// (8B/edge, L2-resident). Output 12 scalars per node (A0^h, A1^h, D^h).
__global__ void k_agg1s(const float* __restrict__ x, const int* __restrict__ offs,
                        const int* __restrict__ ssrc, const float* __restrict__ cvec,
                        int N, float4* Sa, float4* Sb, float4* Sc){
    int n = blockIdx.x * blockDim.x + threadIdx.x;
    if (n >= N) return;
    float4 cs0 = ((const float4*)cvec)[0];
    float4 cs1 = ((const float4*)cvec)[1];
    float4 cd0 = ((const float4*)cvec)[2];
    float4 cd1 = ((const float4*)cvec)[3];
    float c0[4] = {cs0.x, cs0.y, cs0.z, cs0.w};
    float c1[4] = {cs1.x, cs1.y, cs1.z, cs1.w};
    float2 xn = ((const float2*)x)[n];
    float ad[4] = {xn.x*cd0.x + xn.y*cd1.x, xn.x*cd0.y + xn.y*cd1.y,
                   xn.x*cd0.z + xn.y*cd1.z, xn.x*cd0.w + xn.y*cd1.w};
    float A0[4] = {0,0,0,0}, A1[4] = {0,0,0,0}, D[4] = {0,0,0,0};
    int beg = offs[n], end = offs[n + 1];
    for (int j = beg; j < end; j++){
        int s = ssrc[j];
        float2 xs = ((const float2*)x)[s];
#pragma unroll
        for (int h = 0; h < HEADS; h++){
            float e = xs.x * c0[h] + xs.y * c1[h] + ad[h];
            float w = expf(lrelu(e));
            A0[h] += w * xs.x;
            A1[h] += w * xs.y;
            D[h]  += w;
        }
    }
    Sa[n] = make_float4(A0[0], A0[1], A0[2], A0[3]);
    Sb[n] = make_float4(A1[0], A1[1], A1[2], A1[3]);
    Sc[n] = make_float4(D[0],  D[1],  D[2],  D[3]);
}

// expand scalars -> h1[N,256] = elu((A0^h*W1[0,j] + A1^h*W1[1,j])/D^h + b1[j])
__global__ void k_h1(const float4* __restrict__ Sa, const float4* __restrict__ Sb,
                     const float4* __restrict__ Sc, const float* __restrict__ W1,
                     const float* __restrict__ b1, int N, float* __restrict__ h1){
    int wv = threadIdx.x >> 6, lane = threadIdx.x & 63;
    int n = blockIdx.x * 4 + wv;
    if (n >= N) return;
    float4 A0 = Sa[n], A1 = Sb[n], Dv = Sc[n];
    float a0[4] = {A0.x, A0.y, A0.z, A0.w};
    float a1[4] = {A1.x, A1.y, A1.z, A1.w};
    float dv[4] = {Dv.x, Dv.y, Dv.z, Dv.w};
    size_t base = (size_t)n * 256;
#pragma unroll
    for (int h = 0; h < HEADS; h++){
        int j = h * HID + lane;
        float u = (a0[h] * W1[j] + a1[h] * W1[256 + j]) / dv[h] + b1[j];
        h1[base + j] = elu_(u);
    }
}

// xh2 = h1 @ W2 with W2 staged in LDS; wave handles 4 nodes (uniform-broadcast
// h1 row loads, 16 FMA per 4 ds_read). Also fuses the attention dots.
__global__ void __launch_bounds__(512)
k_gemm2(const float* __restrict__ h1, const float* __restrict__ W2,
        const float* __restrict__ as2, const float* __restrict__ ad2,
        int N, float* __restrict__ xh2, float* __restrict__ asrc, float* __restrict__ adst){
    __shared__ float W2s[256 * 64];
    for (int i = threadIdx.x; i < 4096; i += 512)
        ((float4*)W2s)[i] = ((const float4*)W2)[i];
    __syncthreads();
    int lane = threadIdx.x & 63, wv = threadIdx.x >> 6;
    float asw = as2[lane], adw = ad2[lane];
    int ngroup = (N + 3) / 4;
    for (int g = blockIdx.x * 8 + wv; g < ngroup; g += gridDim.x * 8){
        int n0 = g * 4;
        const float4* A0 = (const float4*)(h1 + (size_t)min(n0    , N - 1) * 256);
        const float4* A1 = (const float4*)(h1 + (size_t)min(n0 + 1, N - 1) * 256);
        const float4* A2 = (const float4*)(h1 + (size_t)min(n0 + 2, N - 1) * 256);
        const float4* A3 = (const float4*)(h1 + (size_t)min(n0 + 3, N - 1) * 256);
        float ac0 = 0.f, ac1 = 0.f, ac2 = 0.f, ac3 = 0.f;
#pragma unroll 4
        for (int k4 = 0; k4 < 64; k4++){
            float4 a0 = A0[k4], a1 = A1[k4], a2 = A2[k4], a3 = A3[k4];
            const float* wp = W2s + k4 * 256 + lane;
            float w0 = wp[0], w1 = wp[64], w2 = wp[128], w3 = wp[192];
            ac0 += a0.x*w0 + a0.y*w1 + a0.z*w2 + a0.w*w3;
            ac1 += a1.x*w0 + a1.y*w1 + a1.z*w2 + a1.w*w3;
            ac2 += a2.x*w0 + a2.y*w1 + a2.z*w2 + a2.w*w3;
            ac3 += a3.x*w0 + a3.y*w1 + a3.z*w2 + a3.w*w3;
        }
        float accs[4] = {ac0, ac1, ac2, ac3};
#pragma unroll
        for (int m = 0; m < 4; m++){
            int n = n0 + m;
            if (n >= N) break;
            float ac = accs[m];
            xh2[(size_t)n * 64 + lane] = ac;
            float ps = ac * asw, pd = ac * adw;
#pragma unroll
            for (int off = 32; off; off >>= 1){
                ps += __shfl_xor(ps, off, 64);
                pd += __shfl_xor(pd, off, 64);
            }
            if (lane == 0){ asrc[n] = ps; adst[n] = pd; }
        }
    }
}

__global__ void k_agg2(const float* __restrict__ xh2, const float* __restrict__ asrc,
                       const float* __restrict__ adst, const int* __restrict__ offs,
                       const int* __restrict__ ssrc, const float* __restrict__ b2,
                       int N, float* __restrict__ h2){
    int wave = threadIdx.x >> 6, lane = threadIdx.x & 63;
    int n = blockIdx.x * 4 + wave;
    if (n >= N) return;
    float ad = adst[n];
    float acc = 0.f, den = 0.f;
    int beg = offs[n], end = offs[n + 1];
    for (int j = beg; j < end; j++){
        int s = ssrc[j];
        float w = expf(lrelu(asrc[s] + ad));
        acc += w * xh2[(size_t)s * 64 + lane];
        den += w;
    }
    h2[(size_t)n * 64 + lane] = elu_(acc / den + b2[lane]);
}

// global mean pool: batch is SORTED -> register run-accumulation per chunk
__global__ void k_pool(const float* __restrict__ h2, const int* __restrict__ batch,
                       int N, float* sums, int* counts){
    int lane = threadIdx.x & 63;   // blockDim = 64
    int chunk = (N + gridDim.x - 1) / gridDim.x;
    int beg = blockIdx.x * chunk;
    int end = min(beg + chunk, N);
    if (beg >= end) return;
    float acc = 0.f; int cnt = 0; int cur = batch[beg];
    for (int n = beg; n < end; n++){
        int g = batch[n];
        if (g != cur){
            atomicAdd(&sums[cur * HID + lane], acc);
            if (lane == 0) atomicAdd(&counts[cur], cnt);
            acc = 0.f; cnt = 0; cur = g;
        }
        acc += h2[(size_t)n * HID + lane];
        cnt++;
    }
    atomicAdd(&sums[cur * HID + lane], acc);
    if (lane == 0) atomicAdd(&counts[cur], cnt);
}

__global__ void k_final(const float* __restrict__ sums, const int* __restrict__ counts,
                        const float* __restrict__ Wl, const float* __restrict__ bl,
                        float* out){
    int t = threadIdx.x;
    if (t >= GR * 2) return;
    int g = t >> 1, task = t & 1;
    float c = (float)max(counts[g], 1);
    float acc = 0.f;
#pragma unroll
    for (int k = 0; k < HID; k++)
        acc += (sums[g * HID + k] / c) * Wl[k * 2 + task];
    out[t] = acc + bl[task];
}

extern "C" void kernel_launch(void* const* d_in, const int* in_sizes, int n_in,
                              void* d_out, int out_size, void* d_ws, size_t ws_size,
                              hipStream_t stream) {
    const float* x    = (const float*)d_in[0];
    const int*   ei   = (const int*)  d_in[1];
    const int*   batch= (const int*)  d_in[2];
    const float* W1   = (const float*)d_in[3];
    const float* as1  = (const float*)d_in[4];
    const float* ad1  = (const float*)d_in[5];
    const float* b1   = (const float*)d_in[6];
    const float* W2   = (const float*)d_in[7];
    const float* as2  = (const float*)d_in[8];
    const float* ad2  = (const float*)d_in[9];
    const float* b2   = (const float*)d_in[10];
    const float* Wl   = (const float*)d_in[11];
    const float* bl   = (const float*)d_in[12];
    float* out = (float*)d_out;

    int N  = in_sizes[0] / 2;
    int E  = in_sizes[1] / 2;
    int Et = E + N;
    const int* srcp = ei;
    const int* dstp = ei + E;

    char* p = (char*)d_ws;
    auto alloc = [&](size_t bytes)->char* {
        char* r = p; p += (bytes + 255) & ~(size_t)255; return r;
    };
    int*    deg    = (int*)   alloc((size_t)N * 4);
    int*    offs   = (int*)   alloc((size_t)(N + 1) * 4);
    int*    cursor = (int*)   alloc((size_t)N * 4);
    int*    bsum   = (int*)   alloc(1024 * 4);
    int*    ssrc   = (int*)   alloc((size_t)Et * 4);
    float*  cvec   = (float*) alloc(16 * 4);
    float4* Sa     = (float4*)alloc((size_t)N * 16);
    float4* Sb     = (float4*)alloc((size_t)N * 16);
    float4* Sc     = (float4*)alloc((size_t)N * 16);
    float*  asrc2  = (float*) alloc((size_t)N * 4);
    float*  adst2  = (float*) alloc((size_t)N * 4);
    float*  sums   = (float*) alloc((size_t)GR * HID * 4);
    int*    counts = (int*)   alloc((size_t)GR * 4);
    float*  h1     = (float*) alloc((size_t)N * 256 * 4);
    float*  xh2    = (float*) alloc((size_t)N * 64 * 4);
    float*  h2     = (float*) alloc((size_t)N * 64 * 4);

    int nb1024 = (N + 1023) / 1024;
    int nwg4   = (N + 3) / 4;

    k_init <<<(N + 255) / 256, 256, 0, stream>>>(deg, sums, counts, N);
    k_hist <<<(E + 255) / 256, 256, 0, stream>>>(dstp, E, deg);
    k_scan1<<<nb1024, 1024, 0, stream>>>(deg, N, offs, bsum);
    k_scan2<<<1, 64, 0, stream>>>(bsum, nb1024);
    k_scan3<<<nb1024, 1024, 0, stream>>>(offs, bsum, cursor, N, Et);
    k_fill <<<(Et + 255) / 256, 256, 0, stream>>>(srcp, dstp, E, Et, cursor, ssrc);

    k_const<<<1, 64, 0, stream>>>(W1, as1, ad1, cvec);
    k_agg1s<<<(N + 255) / 256, 256, 0, stream>>>(x, offs, ssrc, cvec, N, Sa, Sb, Sc);
    k_h1   <<<nwg4, 256, 0, stream>>>(Sa, Sb, Sc, W1, b1, N, h1);
    k_gemm2<<<512, 512, 0, stream>>>(h1, W2, as2, ad2, N, xh2, asrc2, adst2);
    k_agg2 <<<nwg4, 256, 0, stream>>>(xh2, asrc2, adst2, offs, ssrc, b2, N, h2);

    k_pool <<<512, 64, 0, stream>>>(h2, batch, N, sums, counts);
    k_final<<<1, 128, 0, stream>>>(sums, counts, Wl, bl, out);
}

// Round 3
// 626.106 us; speedup vs baseline: 1.8475x; 1.1338x over previous
//
#include <hip/hip_runtime.h>
#include <math.h>

#define HID 64
#define HEADS 4
#define GR 64
#define NEG 0.2f
#define NB 8   // nodes per batch in fused layer-2 GEMM

__device__ __forceinline__ float lrelu(float v){ return v > 0.f ? v : NEG * v; }
__device__ __forceinline__ float elu_(float v){ return v > 0.f ? v : expm1f(v); }

// deg=1 (self-loop), zero pooled sums/counts  (must run EVERY call: harness
// does not re-poison ws between timed replays)
__global__ void k_init(int* deg, float* sums, int* counts, int N){
    int i = blockIdx.x * blockDim.x + threadIdx.x;
    if (i < N) deg[i] = 1;
    if (i < GR * HID) sums[i] = 0.f;
    if (i < GR) counts[i] = 0;
}

__global__ void k_hist(const int* __restrict__ dst, int E, int* deg){
    int i = blockIdx.x * blockDim.x + threadIdx.x;
    if (i < E) atomicAdd(&deg[dst[i]], 1);
}

__global__ void k_scan1(const int* __restrict__ deg, int N, int* offs, int* bsum){
    __shared__ int sh[1024];
    int i = blockIdx.x * 1024 + threadIdx.x;
    int v = (i < N) ? deg[i] : 0;
    sh[threadIdx.x] = v;
    __syncthreads();
    for (int off = 1; off < 1024; off <<= 1){
        int t = (threadIdx.x >= off) ? sh[threadIdx.x - off] : 0;
        __syncthreads();
        sh[threadIdx.x] += t;
        __syncthreads();
    }
    if (i < N) offs[i] = sh[threadIdx.x] - v;
    if (threadIdx.x == 1023) bsum[blockIdx.x] = sh[1023];
}

// parallel exclusive scan of block sums (nb <= 1024)
__global__ void k_scan2(int* bsum, int nb){
    __shared__ int sh[1024];
    int t = threadIdx.x;
    int v = (t < nb) ? bsum[t] : 0;
    sh[t] = v;
    __syncthreads();
    for (int off = 1; off < 1024; off <<= 1){
        int u = (t >= off) ? sh[t - off] : 0;
        __syncthreads();
        sh[t] += u;
        __syncthreads();
    }
    if (t < nb) bsum[t] = sh[t] - v;
}

__global__ void k_scan3(int* offs, const int* __restrict__ bsum, int* cursor, int N, int Et){
    int i = blockIdx.x * 1024 + threadIdx.x;
    if (i < N){
        int o = offs[i] + bsum[blockIdx.x];
        offs[i] = o;
        cursor[i] = o;
    }
    if (i == 0) offs[N] = Et;
}

__global__ void k_fill(const int* __restrict__ src, const int* __restrict__ dst,
                       int E, int Et, int* cursor, int* ssrc){
    int i = blockIdx.x * blockDim.x + threadIdx.x;
    if (i >= Et) return;
    int s, d;
    if (i < E){ s = src[i]; d = dst[i]; } else { s = d = i - E; }
    int pos = atomicAdd(&cursor[d], 1);
    ssrc[pos] = s;
}

// attention-projection constants: cvec = [cs0(4), cs1(4), cd0(4), cd1(4)]
__global__ void k_const(const float* __restrict__ W1, const float* __restrict__ as1,
                        const float* __restrict__ ad1, float* cvec){
    int lane = threadIdx.x;      // 64 threads
#pragma unroll
    for (int h = 0; h < HEADS; h++){
        int j = h * HID + lane;
        float s0 = W1[j]       * as1[j];
        float s1 = W1[256 + j] * as1[j];
        float d0 = W1[j]       * ad1[j];
        float d1 = W1[256 + j] * ad1[j];
#pragma unroll
        for (int off = 32; off; off >>= 1){
            s0 += __shfl_xor(s0, off, 64);
            s1 += __shfl_xor(s1, off, 64);
            d0 += __shfl_xor(d0, off, 64);
            d1 += __shfl_xor(d1, off, 64);
        }
        if (lane == 0){
            cvec[h] = s0; cvec[4 + h] = s1; cvec[8 + h] = d0; cvec[12 + h] = d1;
        }
    }
}

// layer-1 aggregation via rank-2 trick: thread per dst node, gather only x[src]
// (8B/edge, L2-resident). Output 12 scalars per node (A0^h, A1^h, D^h).
__global__ void k_agg1s(const float* __restrict__ x, const int* __restrict__ offs,
                        const int* __restrict__ ssrc, const float* __restrict__ cvec,
                        int N, float4* Sa, float4* Sb, float4* Sc){
    int n = blockIdx.x * blockDim.x + threadIdx.x;
    if (n >= N) return;
    float4 cs0 = ((const float4*)cvec)[0];
    float4 cs1 = ((const float4*)cvec)[1];
    float4 cd0 = ((const float4*)cvec)[2];
    float4 cd1 = ((const float4*)cvec)[3];
    float c0[4] = {cs0.x, cs0.y, cs0.z, cs0.w};
    float c1[4] = {cs1.x, cs1.y, cs1.z, cs1.w};
    float2 xn = ((const float2*)x)[n];
    float ad[4] = {xn.x*cd0.x + xn.y*cd1.x, xn.x*cd0.y + xn.y*cd1.y,
                   xn.x*cd0.z + xn.y*cd1.z, xn.x*cd0.w + xn.y*cd1.w};
    float A0[4] = {0,0,0,0}, A1[4] = {0,0,0,0}, D[4] = {0,0,0,0};
    int beg = offs[n], end = offs[n + 1];
    for (int j = beg; j < end; j++){
        int s = ssrc[j];
        float2 xs = ((const float2*)x)[s];
#pragma unroll
        for (int h = 0; h < HEADS; h++){
            float e = xs.x * c0[h] + xs.y * c1[h] + ad[h];
            float w = expf(lrelu(e));
            A0[h] += w * xs.x;
            A1[h] += w * xs.y;
            D[h]  += w;
        }
    }
    Sa[n] = make_float4(A0[0], A0[1], A0[2], A0[3]);
    Sb[n] = make_float4(A1[0], A1[1], A1[2], A1[3]);
    Sc[n] = make_float4(D[0],  D[1],  D[2],  D[3]);
}

// Fused: h1 row computed in-register from 12 scalars, GEMM vs W2 (W2 in VGPRs,
// 4-wave k-split), LDS broadcast of h, LDS partial reduce, attention dots.
// wave w owns k-slice [64w,64w+64); lane = output col AND k-elem 64w+lane.
__global__ void __launch_bounds__(256)
k_l2fused(const float* __restrict__ Saf, const float* __restrict__ Sbf,
          const float* __restrict__ Scf, const float* __restrict__ W1,
          const float* __restrict__ b1, const float* __restrict__ W2,
          const float* __restrict__ as2, const float* __restrict__ ad2,
          int N, float* __restrict__ xh2, float* __restrict__ asrc,
          float* __restrict__ adst){
    __shared__ float hS[NB][256];
    __shared__ float partS[4][NB][64];
    int lane = threadIdx.x & 63, w = threadIdx.x >> 6;
    int kk = w * 64 + lane;
    float w2r[64];
#pragma unroll
    for (int j = 0; j < 64; j++) w2r[j] = W2[(w * 64 + j) * 64 + lane];
    float w10 = W1[kk], w11 = W1[256 + kk], b1k = b1[kk];
    float asw = as2[lane], adw = ad2[lane];

    int nbatches = (N + NB - 1) / NB;
    for (int b = blockIdx.x; b < nbatches; b += gridDim.x){
        int n0 = b * NB;
        // phase 1: expand h rows from scalars
#pragma unroll
        for (int m = 0; m < NB; m++){
            int n = n0 + m;
            if (n < N){
                float A0 = Saf[n * 4 + w], A1 = Sbf[n * 4 + w], Dv = Scf[n * 4 + w];
                float u = (A0 * w10 + A1 * w11) / Dv + b1k;
                hS[m][kk] = elu_(u);
            }
        }
        __syncthreads();
        // phase 2: MAC (broadcast ds_read_b128, W2 in regs)
#pragma unroll
        for (int m = 0; m < NB; m++){
            float acc = 0.f;
            const float4* hp = (const float4*)&hS[m][w * 64];
#pragma unroll
            for (int q = 0; q < 16; q++){
                float4 hv = hp[q];
                acc += hv.x * w2r[4*q] + hv.y * w2r[4*q+1]
                     + hv.z * w2r[4*q+2] + hv.w * w2r[4*q+3];
            }
            partS[w][m][lane] = acc;
        }
        __syncthreads();
        // phase 3: cross-wave reduce + epilogue (wave handles m = w, w+4)
        for (int m = w; m < NB; m += 4){
            int n = n0 + m;
            if (n < N){
                float acc = partS[0][m][lane] + partS[1][m][lane]
                          + partS[2][m][lane] + partS[3][m][lane];
                xh2[(size_t)n * 64 + lane] = acc;
                float ps = acc * asw, pd = acc * adw;
#pragma unroll
                for (int off = 32; off; off >>= 1){
                    ps += __shfl_xor(ps, off, 64);
                    pd += __shfl_xor(pd, off, 64);
                }
                if (lane == 0){ asrc[n] = ps; adst[n] = pd; }
            }
        }
        __syncthreads();
    }
}

// layer-2 aggregation fused with global mean pool: contiguous node chunk per
// wave, register run-accumulation keyed by graph id (batch sorted), atomic
// flush on graph change / chunk end.
__global__ void k_agg2p(const float* __restrict__ xh2, const float* __restrict__ asrc,
                        const float* __restrict__ adst, const int* __restrict__ offs,
                        const int* __restrict__ ssrc, const float* __restrict__ b2,
                        const int* __restrict__ batch, int N,
                        float* sums, int* counts){
    int lane = threadIdx.x & 63, wv = threadIdx.x >> 6;  // 4 waves/block
    int wid = blockIdx.x * 4 + wv;
    int nw = gridDim.x * 4;
    int chunk = (N + nw - 1) / nw;
    int beg = wid * chunk, end = min(beg + chunk, N);
    if (beg >= end) return;
    float b2l = b2[lane];
    float pacc = 0.f; int pcnt = 0; int cur = batch[beg];
    for (int n = beg; n < end; n++){
        float ad = adst[n];
        float acc = 0.f, den = 0.f;
        int e0 = offs[n], e1 = offs[n + 1];
        int s = ssrc[e0];
        for (int j = e0; j < e1; j++){
            int snext = (j + 1 < e1) ? ssrc[j + 1] : 0;   // prefetch
            float as_ = asrc[s];
            const float* row = xh2 + (size_t)s * 64;
            float wgt = expf(lrelu(as_ + ad));
            acc += wgt * row[lane];
            den += wgt;
            s = snext;
        }
        float h2v = elu_(acc / den + b2l);
        int g = batch[n];
        if (g != cur){
            atomicAdd(&sums[cur * HID + lane], pacc);
            if (lane == 0) atomicAdd(&counts[cur], pcnt);
            pacc = 0.f; pcnt = 0; cur = g;
        }
        pacc += h2v; pcnt++;
    }
    atomicAdd(&sums[cur * HID + lane], pacc);
    if (lane == 0) atomicAdd(&counts[cur], pcnt);
}

__global__ void k_final(const float* __restrict__ sums, const int* __restrict__ counts,
                        const float* __restrict__ Wl, const float* __restrict__ bl,
                        float* out){
    int t = threadIdx.x;
    if (t >= GR * 2) return;
    int g = t >> 1, task = t & 1;
    float c = (float)max(counts[g], 1);
    float acc = 0.f;
#pragma unroll
    for (int k = 0; k < HID; k++)
        acc += (sums[g * HID + k] / c) * Wl[k * 2 + task];
    out[t] = acc + bl[task];
}

extern "C" void kernel_launch(void* const* d_in, const int* in_sizes, int n_in,
                              void* d_out, int out_size, void* d_ws, size_t ws_size,
                              hipStream_t stream) {
    const float* x    = (const float*)d_in[0];
    const int*   ei   = (const int*)  d_in[1];
    const int*   batch= (const int*)  d_in[2];
    const float* W1   = (const float*)d_in[3];
    const float* as1  = (const float*)d_in[4];
    const float* ad1  = (const float*)d_in[5];
    const float* b1   = (const float*)d_in[6];
    const float* W2   = (const float*)d_in[7];
    const float* as2  = (const float*)d_in[8];
    const float* ad2  = (const float*)d_in[9];
    const float* b2   = (const float*)d_in[10];
    const float* Wl   = (const float*)d_in[11];
    const float* bl   = (const float*)d_in[12];
    float* out = (float*)d_out;

    int N  = in_sizes[0] / 2;
    int E  = in_sizes[1] / 2;
    int Et = E + N;
    const int* srcp = ei;
    const int* dstp = ei + E;

    char* p = (char*)d_ws;
    auto alloc = [&](size_t bytes)->char* {
        char* r = p; p += (bytes + 255) & ~(size_t)255; return r;
    };
    int*    deg    = (int*)   alloc((size_t)N * 4);
    int*    offs   = (int*)   alloc((size_t)(N + 1) * 4);
    int*    cursor = (int*)   alloc((size_t)N * 4);
    int*    bsum   = (int*)   alloc(1024 * 4);
    int*    ssrc   = (int*)   alloc((size_t)Et * 4);
    float*  cvec   = (float*) alloc(16 * 4);
    float4* Sa     = (float4*)alloc((size_t)N * 16);
    float4* Sb     = (float4*)alloc((size_t)N * 16);
    float4* Sc     = (float4*)alloc((size_t)N * 16);
    float*  asrc2  = (float*) alloc((size_t)N * 4);
    float*  adst2  = (float*) alloc((size_t)N * 4);
    float*  sums   = (float*) alloc((size_t)GR * HID * 4);
    int*    counts = (int*)   alloc((size_t)GR * 4);
    float*  xh2    = (float*) alloc((size_t)N * 64 * 4);

    int nb1024 = (N + 1023) / 1024;

    k_init <<<(N + 255) / 256, 256, 0, stream>>>(deg, sums, counts, N);
    k_hist <<<(E + 255) / 256, 256, 0, stream>>>(dstp, E, deg);
    k_scan1<<<nb1024, 1024, 0, stream>>>(deg, N, offs, bsum);
    k_scan2<<<1, 1024, 0, stream>>>(bsum, nb1024);
    k_scan3<<<nb1024, 1024, 0, stream>>>(offs, bsum, cursor, N, Et);
    k_fill <<<(Et + 255) / 256, 256, 0, stream>>>(srcp, dstp, E, Et, cursor, ssrc);

    k_const<<<1, 64, 0, stream>>>(W1, as1, ad1, cvec);
    k_agg1s<<<(N + 255) / 256, 256, 0, stream>>>(x, offs, ssrc, cvec, N, Sa, Sb, Sc);
    k_l2fused<<<2048, 256, 0, stream>>>((const float*)Sa, (const float*)Sb,
                                        (const float*)Sc, W1, b1, W2, as2, ad2,
                                        N, xh2, asrc2, adst2);
    k_agg2p<<<1024, 256, 0, stream>>>(xh2, asrc2, adst2, offs, ssrc, b2,
                                      batch, N, sums, counts);
    k_final<<<1, 128, 0, stream>>>(sums, counts, Wl, bl, out);
}

// Round 4
// 422.158 us; speedup vs baseline: 2.7400x; 1.4831x over previous
//
#include <hip/hip_runtime.h>
#include <math.h>

#define HID 64
#define HEADS 4
#define GR 64
#define NEG 0.2f
#define NB 8   // nodes per batch in fused layer-2 GEMM

__device__ __forceinline__ float lrelu(float v){ return v > 0.f ? v : NEG * v; }
__device__ __forceinline__ float elu_(float v){ return v > 0.f ? v : expm1f(v); }

// deg=1 (self-loop), zero pooled sums/counts  (must run EVERY call: harness
// does not re-poison ws between timed replays)
__global__ void k_init(int* deg, float* sums, int* counts, int N){
    int i = blockIdx.x * blockDim.x + threadIdx.x;
    if (i < N) deg[i] = 1;
    if (i < GR * HID) sums[i] = 0.f;
    if (i < GR) counts[i] = 0;
}

__global__ void k_hist(const int* __restrict__ dst, int E, int* deg){
    int i = blockIdx.x * blockDim.x + threadIdx.x;
    if (i < E) atomicAdd(&deg[dst[i]], 1);
}

__global__ void k_scan1(const int* __restrict__ deg, int N, int* offs, int* bsum){
    __shared__ int sh[1024];
    int i = blockIdx.x * 1024 + threadIdx.x;
    int v = (i < N) ? deg[i] : 0;
    sh[threadIdx.x] = v;
    __syncthreads();
    for (int off = 1; off < 1024; off <<= 1){
        int t = (threadIdx.x >= off) ? sh[threadIdx.x - off] : 0;
        __syncthreads();
        sh[threadIdx.x] += t;
        __syncthreads();
    }
    if (i < N) offs[i] = sh[threadIdx.x] - v;
    if (threadIdx.x == 1023) bsum[blockIdx.x] = sh[1023];
}

// parallel exclusive scan of block sums (nb <= 1024)
__global__ void k_scan2(int* bsum, int nb){
    __shared__ int sh[1024];
    int t = threadIdx.x;
    int v = (t < nb) ? bsum[t] : 0;
    sh[t] = v;
    __syncthreads();
    for (int off = 1; off < 1024; off <<= 1){
        int u = (t >= off) ? sh[t - off] : 0;
        __syncthreads();
        sh[t] += u;
        __syncthreads();
    }
    if (t < nb) bsum[t] = sh[t] - v;
}

__global__ void k_scan3(int* offs, const int* __restrict__ bsum, int* cursor, int N, int Et){
    int i = blockIdx.x * 1024 + threadIdx.x;
    if (i < N){
        int o = offs[i] + bsum[blockIdx.x];
        offs[i] = o;
        cursor[i] = o;
    }
    if (i == 0) offs[N] = Et;
}

__global__ void k_fill(const int* __restrict__ src, const int* __restrict__ dst,
                       int E, int Et, int* cursor, int* ssrc){
    int i = blockIdx.x * blockDim.x + threadIdx.x;
    if (i >= Et) return;
    int s, d;
    if (i < E){ s = src[i]; d = dst[i]; } else { s = d = i - E; }
    int pos = atomicAdd(&cursor[d], 1);
    ssrc[pos] = s;
}

// attention-projection constants: cvec = [cs0(4), cs1(4), cd0(4), cd1(4)]
__global__ void k_const(const float* __restrict__ W1, const float* __restrict__ as1,
                        const float* __restrict__ ad1, float* cvec){
    int lane = threadIdx.x;      // 64 threads
#pragma unroll
    for (int h = 0; h < HEADS; h++){
        int j = h * HID + lane;
        float s0 = W1[j]       * as1[j];
        float s1 = W1[256 + j] * as1[j];
        float d0 = W1[j]       * ad1[j];
        float d1 = W1[256 + j] * ad1[j];
#pragma unroll
        for (int off = 32; off; off >>= 1){
            s0 += __shfl_xor(s0, off, 64);
            s1 += __shfl_xor(s1, off, 64);
            d0 += __shfl_xor(d0, off, 64);
            d1 += __shfl_xor(d1, off, 64);
        }
        if (lane == 0){
            cvec[h] = s0; cvec[4 + h] = s1; cvec[8 + h] = d0; cvec[12 + h] = d1;
        }
    }
}

// layer-1 aggregation via rank-2 trick: thread per dst node, gather only x[src]
// (8B/edge, L2-resident). Output 12 scalars per node (A0^h, A1^h, D^h).
// Edge loop unrolled x4 for memory-level parallelism.
__global__ void k_agg1s(const float* __restrict__ x, const int* __restrict__ offs,
                        const int* __restrict__ ssrc, const float* __restrict__ cvec,
                        int N, float4* Sa, float4* Sb, float4* Sc){
    int n = blockIdx.x * blockDim.x + threadIdx.x;
    if (n >= N) return;
    float4 cs0 = ((const float4*)cvec)[0];
    float4 cs1 = ((const float4*)cvec)[1];
    float4 cd0 = ((const float4*)cvec)[2];
    float4 cd1 = ((const float4*)cvec)[3];
    float c0[4] = {cs0.x, cs0.y, cs0.z, cs0.w};
    float c1[4] = {cs1.x, cs1.y, cs1.z, cs1.w};
    float2 xn = ((const float2*)x)[n];
    float ad[4] = {xn.x*cd0.x + xn.y*cd1.x, xn.x*cd0.y + xn.y*cd1.y,
                   xn.x*cd0.z + xn.y*cd1.z, xn.x*cd0.w + xn.y*cd1.w};
    float A0[4] = {0,0,0,0}, A1[4] = {0,0,0,0}, D[4] = {0,0,0,0};
    int beg = offs[n], end = offs[n + 1];
    int j = beg;
    for (; j + 4 <= end; j += 4){
        int s0 = ssrc[j], s1 = ssrc[j+1], s2 = ssrc[j+2], s3 = ssrc[j+3];
        float2 xa = ((const float2*)x)[s0];
        float2 xb = ((const float2*)x)[s1];
        float2 xc = ((const float2*)x)[s2];
        float2 xd = ((const float2*)x)[s3];
#pragma unroll
        for (int h = 0; h < HEADS; h++){
            float wa = __expf(lrelu(xa.x * c0[h] + xa.y * c1[h] + ad[h]));
            float wb = __expf(lrelu(xb.x * c0[h] + xb.y * c1[h] + ad[h]));
            float wc = __expf(lrelu(xc.x * c0[h] + xc.y * c1[h] + ad[h]));
            float wd = __expf(lrelu(xd.x * c0[h] + xd.y * c1[h] + ad[h]));
            A0[h] += wa * xa.x + wb * xb.x + wc * xc.x + wd * xd.x;
            A1[h] += wa * xa.y + wb * xb.y + wc * xc.y + wd * xd.y;
            D[h]  += wa + wb + wc + wd;
        }
    }
    for (; j < end; j++){
        int s = ssrc[j];
        float2 xs = ((const float2*)x)[s];
#pragma unroll
        for (int h = 0; h < HEADS; h++){
            float e = xs.x * c0[h] + xs.y * c1[h] + ad[h];
            float w = __expf(lrelu(e));
            A0[h] += w * xs.x;
            A1[h] += w * xs.y;
            D[h]  += w;
        }
    }
    Sa[n] = make_float4(A0[0], A0[1], A0[2], A0[3]);
    Sb[n] = make_float4(A1[0], A1[1], A1[2], A1[3]);
    Sc[n] = make_float4(D[0],  D[1],  D[2],  D[3]);
}

// Fused: h1 row computed in-register from 12 scalars, GEMM vs W2 (W2 in VGPRs,
// 4-wave k-split), LDS broadcast of h, LDS partial reduce, attention dots.
__global__ void __launch_bounds__(256)
k_l2fused(const float* __restrict__ Saf, const float* __restrict__ Sbf,
          const float* __restrict__ Scf, const float* __restrict__ W1,
          const float* __restrict__ b1, const float* __restrict__ W2,
          const float* __restrict__ as2, const float* __restrict__ ad2,
          int N, float* __restrict__ xh2, float* __restrict__ asrc,
          float* __restrict__ adst){
    __shared__ float hS[NB][256];
    __shared__ float partS[4][NB][64];
    int lane = threadIdx.x & 63, w = threadIdx.x >> 6;
    int kk = w * 64 + lane;
    float w2r[64];
#pragma unroll
    for (int j = 0; j < 64; j++) w2r[j] = W2[(w * 64 + j) * 64 + lane];
    float w10 = W1[kk], w11 = W1[256 + kk], b1k = b1[kk];
    float asw = as2[lane], adw = ad2[lane];

    int nbatches = (N + NB - 1) / NB;
    for (int b = blockIdx.x; b < nbatches; b += gridDim.x){
        int n0 = b * NB;
#pragma unroll
        for (int m = 0; m < NB; m++){
            int n = n0 + m;
            if (n < N){
                float A0 = Saf[n * 4 + w], A1 = Sbf[n * 4 + w], Dv = Scf[n * 4 + w];
                float u = (A0 * w10 + A1 * w11) / Dv + b1k;
                hS[m][kk] = elu_(u);
            }
        }
        __syncthreads();
#pragma unroll
        for (int m = 0; m < NB; m++){
            float acc = 0.f;
            const float4* hp = (const float4*)&hS[m][w * 64];
#pragma unroll
            for (int q = 0; q < 16; q++){
                float4 hv = hp[q];
                acc += hv.x * w2r[4*q] + hv.y * w2r[4*q+1]
                     + hv.z * w2r[4*q+2] + hv.w * w2r[4*q+3];
            }
            partS[w][m][lane] = acc;
        }
        __syncthreads();
        for (int m = w; m < NB; m += 4){
            int n = n0 + m;
            if (n < N){
                float acc = partS[0][m][lane] + partS[1][m][lane]
                          + partS[2][m][lane] + partS[3][m][lane];
                xh2[(size_t)n * 64 + lane] = acc;
                float ps = acc * asw, pd = acc * adw;
#pragma unroll
                for (int off = 32; off; off >>= 1){
                    ps += __shfl_xor(ps, off, 64);
                    pd += __shfl_xor(pd, off, 64);
                }
                if (lane == 0){ asrc[n] = ps; adst[n] = pd; }
            }
        }
        __syncthreads();
    }
}

// layer-2 aggregation fused with global mean pool. Edge loop unrolled x4 for
// memory-level parallelism (4 independent xh2-row gathers in flight).
__global__ void k_agg2p(const float* __restrict__ xh2, const float* __restrict__ asrc,
                        const float* __restrict__ adst, const int* __restrict__ offs,
                        const int* __restrict__ ssrc, const float* __restrict__ b2,
                        const int* __restrict__ batch, int N,
                        float* sums, int* counts){
    int lane = threadIdx.x & 63, wv = threadIdx.x >> 6;  // 4 waves/block
    int wid = blockIdx.x * 4 + wv;
    int nw = gridDim.x * 4;
    int chunk = (N + nw - 1) / nw;
    int beg = wid * chunk, end = min(beg + chunk, N);
    if (beg >= end) return;
    float b2l = b2[lane];
    float pacc = 0.f; int pcnt = 0; int cur = batch[beg];
    for (int n = beg; n < end; n++){
        float ad = adst[n];
        float acc = 0.f, den = 0.f;
        int e0 = offs[n], e1 = offs[n + 1];
        int j = e0;
        for (; j + 4 <= e1; j += 4){
            int s0 = ssrc[j], s1 = ssrc[j+1], s2 = ssrc[j+2], s3 = ssrc[j+3];
            float a0 = asrc[s0], a1 = asrc[s1], a2 = asrc[s2], a3 = asrc[s3];
            float r0 = xh2[(size_t)s0 * 64 + lane];
            float r1 = xh2[(size_t)s1 * 64 + lane];
            float r2 = xh2[(size_t)s2 * 64 + lane];
            float r3 = xh2[(size_t)s3 * 64 + lane];
            float w0 = __expf(lrelu(a0 + ad));
            float w1 = __expf(lrelu(a1 + ad));
            float w2 = __expf(lrelu(a2 + ad));
            float w3 = __expf(lrelu(a3 + ad));
            acc += w0 * r0 + w1 * r1 + w2 * r2 + w3 * r3;
            den += w0 + w1 + w2 + w3;
        }
        for (; j < e1; j++){
            int s = ssrc[j];
            float wgt = __expf(lrelu(asrc[s] + ad));
            acc += wgt * xh2[(size_t)s * 64 + lane];
            den += wgt;
        }
        float h2v = elu_(acc / den + b2l);
        int g = batch[n];
        if (g != cur){
            atomicAdd(&sums[cur * HID + lane], pacc);
            if (lane == 0) atomicAdd(&counts[cur], pcnt);
            pacc = 0.f; pcnt = 0; cur = g;
        }
        pacc += h2v; pcnt++;
    }
    atomicAdd(&sums[cur * HID + lane], pacc);
    if (lane == 0) atomicAdd(&counts[cur], pcnt);
}

__global__ void k_final(const float* __restrict__ sums, const int* __restrict__ counts,
                        const float* __restrict__ Wl, const float* __restrict__ bl,
                        float* out){
    int t = threadIdx.x;
    if (t >= GR * 2) return;
    int g = t >> 1, task = t & 1;
    float c = (float)max(counts[g], 1);
    float acc = 0.f;
#pragma unroll
    for (int k = 0; k < HID; k++)
        acc += (sums[g * HID + k] / c) * Wl[k * 2 + task];
    out[t] = acc + bl[task];
}

extern "C" void kernel_launch(void* const* d_in, const int* in_sizes, int n_in,
                              void* d_out, int out_size, void* d_ws, size_t ws_size,
                              hipStream_t stream) {
    const float* x    = (const float*)d_in[0];
    const int*   ei   = (const int*)  d_in[1];
    const int*   batch= (const int*)  d_in[2];
    const float* W1   = (const float*)d_in[3];
    const float* as1  = (const float*)d_in[4];
    const float* ad1  = (const float*)d_in[5];
    const float* b1   = (const float*)d_in[6];
    const float* W2   = (const float*)d_in[7];
    const float* as2  = (const float*)d_in[8];
    const float* ad2  = (const float*)d_in[9];
    const float* b2   = (const float*)d_in[10];
    const float* Wl   = (const float*)d_in[11];
    const float* bl   = (const float*)d_in[12];
    float* out = (float*)d_out;

    int N  = in_sizes[0] / 2;
    int E  = in_sizes[1] / 2;
    int Et = E + N;
    const int* srcp = ei;
    const int* dstp = ei + E;

    char* p = (char*)d_ws;
    auto alloc = [&](size_t bytes)->char* {
        char* r = p; p += (bytes + 255) & ~(size_t)255; return r;
    };
    int*    deg    = (int*)   alloc((size_t)N * 4);
    int*    offs   = (int*)   alloc((size_t)(N + 1) * 4);
    int*    cursor = (int*)   alloc((size_t)N * 4);
    int*    bsum   = (int*)   alloc(1024 * 4);
    int*    ssrc   = (int*)   alloc((size_t)Et * 4);
    float*  cvec   = (float*) alloc(16 * 4);
    float4* Sa     = (float4*)alloc((size_t)N * 16);
    float4* Sb     = (float4*)alloc((size_t)N * 16);
    float4* Sc     = (float4*)alloc((size_t)N * 16);
    float*  asrc2  = (float*) alloc((size_t)N * 4);
    float*  adst2  = (float*) alloc((size_t)N * 4);
    float*  sums   = (float*) alloc((size_t)GR * HID * 4);
    int*    counts = (int*)   alloc((size_t)GR * 4);
    float*  xh2    = (float*) alloc((size_t)N * 64 * 4);

    int nb1024 = (N + 1023) / 1024;

    k_init <<<(N + 255) / 256, 256, 0, stream>>>(deg, sums, counts, N);
    k_hist <<<(E + 255) / 256, 256, 0, stream>>>(dstp, E, deg);
    k_scan1<<<nb1024, 1024, 0, stream>>>(deg, N, offs, bsum);
    k_scan2<<<1, 1024, 0, stream>>>(bsum, nb1024);
    k_scan3<<<nb1024, 1024, 0, stream>>>(offs, bsum, cursor, N, Et);
    k_fill <<<(Et + 255) / 256, 256, 0, stream>>>(srcp, dstp, E, Et, cursor, ssrc);

    k_const<<<1, 64, 0, stream>>>(W1, as1, ad1, cvec);
    k_agg1s<<<(N + 255) / 256, 256, 0, stream>>>(x, offs, ssrc, cvec, N, Sa, Sb, Sc);
    k_l2fused<<<2048, 256, 0, stream>>>((const float*)Sa, (const float*)Sb,
                                        (const float*)Sc, W1, b1, W2, as2, ad2,
                                        N, xh2, asrc2, adst2);
    k_agg2p<<<2048, 256, 0, stream>>>(xh2, asrc2, adst2, offs, ssrc, b2,
                                      batch, N, sums, counts);
    k_final<<<1, 128, 0, stream>>>(sums, counts, Wl, bl, out);
}

// Round 5
// 367.722 us; speedup vs baseline: 3.1456x; 1.1480x over previous
//
#include <hip/hip_runtime.h>
#include <math.h>

#define HID 64
#define HEADS 4
#define GR 64
#define NEG 0.2f
#define NB 8        // nodes per batch in fused layer-2 GEMM
#define NBKT_MAX 512
#define BK_SH 8     // 256 nodes per bucket
#define PART_T 2048 // edges per partition tile

__device__ __forceinline__ float lrelu(float v){ return v > 0.f ? v : NEG * v; }
__device__ __forceinline__ float elu_(float v){ return v > 0.f ? v : expm1f(v); }

// deg=1 (self-loop), zero pooled sums/counts/bucket-counts (must run EVERY
// call: harness does not re-poison ws between timed replays)
__global__ void k_init(int* deg, float* sums, int* counts, int* bcnt, int N){
    int i = blockIdx.x * blockDim.x + threadIdx.x;
    if (i < N) deg[i] = 1;
    if (i < GR * HID) sums[i] = 0.f;
    if (i < GR) counts[i] = 0;
    if (i < NBKT_MAX) bcnt[i] = 0;
}

// node-degree histogram + LDS-staged bucket histogram
__global__ void k_hist2(const int* __restrict__ dst, int E, int* deg, int* bcnt){
    __shared__ int bh[NBKT_MAX];
    for (int b = threadIdx.x; b < NBKT_MAX; b += blockDim.x) bh[b] = 0;
    __syncthreads();
    int stride = gridDim.x * blockDim.x;
    for (int i = blockIdx.x * blockDim.x + threadIdx.x; i < E; i += stride){
        int d = dst[i];
        atomicAdd(&deg[d], 1);
        atomicAdd(&bh[d >> BK_SH], 1);
    }
    __syncthreads();
    for (int b = threadIdx.x; b < NBKT_MAX; b += blockDim.x)
        if (bh[b]) atomicAdd(&bcnt[b], bh[b]);
}

__global__ void k_scan1(const int* __restrict__ deg, int N, int* offs, int* bsum){
    __shared__ int sh[1024];
    int i = blockIdx.x * 1024 + threadIdx.x;
    int v = (i < N) ? deg[i] : 0;
    sh[threadIdx.x] = v;
    __syncthreads();
    for (int off = 1; off < 1024; off <<= 1){
        int t = (threadIdx.x >= off) ? sh[threadIdx.x - off] : 0;
        __syncthreads();
        sh[threadIdx.x] += t;
        __syncthreads();
    }
    if (i < N) offs[i] = sh[threadIdx.x] - v;
    if (threadIdx.x == 1023) bsum[blockIdx.x] = sh[1023];
}

// parallel exclusive scan of block sums (nb <= 1024)
__global__ void k_scan2(int* bsum, int nb){
    __shared__ int sh[1024];
    int t = threadIdx.x;
    int v = (t < nb) ? bsum[t] : 0;
    sh[t] = v;
    __syncthreads();
    for (int off = 1; off < 1024; off <<= 1){
        int u = (t >= off) ? sh[t - off] : 0;
        __syncthreads();
        sh[t] += u;
        __syncthreads();
    }
    if (t < nb) bsum[t] = sh[t] - v;
}

__global__ void k_scan3(int* offs, const int* __restrict__ bsum, int N, int Et){
    int i = blockIdx.x * 1024 + threadIdx.x;
    if (i < N) offs[i] += bsum[blockIdx.x];
    if (i == 0) offs[N] = Et;
}

// exclusive scan of bucket counts -> bucket bases + partition cursors
__global__ void k_bscan(const int* __restrict__ bcnt, int* bbase, int* bcursor){
    __shared__ int sh[NBKT_MAX];
    int t = threadIdx.x;     // 512 threads
    int v = bcnt[t];
    sh[t] = v;
    __syncthreads();
    for (int off = 1; off < NBKT_MAX; off <<= 1){
        int u = (t >= off) ? sh[t - off] : 0;
        __syncthreads();
        sh[t] += u;
        __syncthreads();
    }
    bbase[t] = sh[t] - v;
    bcursor[t] = sh[t] - v;
}

// staged partition: per-tile LDS bucket count -> one global reserve per
// (block,bucket) -> scatter packed (dst,src) into block-private runs.
__global__ void __launch_bounds__(256)
k_part(const int* __restrict__ src, const int* __restrict__ dst, int E,
       int* bcursor, unsigned long long* __restrict__ tmp){
    __shared__ int bh[NBKT_MAX];
    __shared__ int gbl[NBKT_MAX];
    int tid = threadIdx.x;
    int base = blockIdx.x * PART_T;
    for (int b = tid; b < NBKT_MAX; b += 256) bh[b] = 0;
    __syncthreads();
#pragma unroll
    for (int r = 0; r < PART_T / 256; r++){
        int i = base + r * 256 + tid;
        if (i < E) atomicAdd(&bh[dst[i] >> BK_SH], 1);
    }
    __syncthreads();
    for (int b = tid; b < NBKT_MAX; b += 256){
        int c = bh[b];
        gbl[b] = c ? atomicAdd(&bcursor[b], c) : 0;
        bh[b] = 0;
    }
    __syncthreads();
#pragma unroll
    for (int r = 0; r < PART_T / 256; r++){
        int i = base + r * 256 + tid;
        if (i < E){
            int s = src[i], d = dst[i];
            int b = d >> BK_SH;
            int rank = atomicAdd(&bh[b], 1);
            tmp[(size_t)(gbl[b] + rank)] = ((unsigned long long)(unsigned)d << 32) | (unsigned)s;
        }
    }
}

// per-bucket CSR emit: block-private ssrc region, LDS per-node rank counters,
// self-loop injected at offs[n] (position 0 of each node's range).
__global__ void __launch_bounds__(256)
k_csr(const unsigned long long* __restrict__ tmp, const int* __restrict__ bbase,
      const int* __restrict__ bcnt, const int* __restrict__ offs,
      int N, int* __restrict__ ssrc){
    __shared__ int rc[256];
    int b = blockIdx.x, tid = threadIdx.x;
    int n0 = b << BK_SH;
    int nloc = min(256, N - n0);
    if (tid < nloc){
        rc[tid] = 0;
        int n = n0 + tid;
        ssrc[offs[n]] = n;     // self-loop first
    }
    __syncthreads();
    int beg = bbase[b], cnt = bcnt[b];
    for (int i = tid; i < cnt; i += 256){
        unsigned long long e = tmp[beg + i];
        int d = (int)(e >> 32);
        int s = (int)(e & 0xffffffffu);
        int pos = offs[d] + 1 + atomicAdd(&rc[d - n0], 1);
        ssrc[pos] = s;
    }
}

// attention-projection constants: cvec = [cs0(4), cs1(4), cd0(4), cd1(4)]
__global__ void k_const(const float* __restrict__ W1, const float* __restrict__ as1,
                        const float* __restrict__ ad1, float* cvec){
    int lane = threadIdx.x;      // 64 threads
#pragma unroll
    for (int h = 0; h < HEADS; h++){
        int j = h * HID + lane;
        float s0 = W1[j]       * as1[j];
        float s1 = W1[256 + j] * as1[j];
        float d0 = W1[j]       * ad1[j];
        float d1 = W1[256 + j] * ad1[j];
#pragma unroll
        for (int off = 32; off; off >>= 1){
            s0 += __shfl_xor(s0, off, 64);
            s1 += __shfl_xor(s1, off, 64);
            d0 += __shfl_xor(d0, off, 64);
            d1 += __shfl_xor(d1, off, 64);
        }
        if (lane == 0){
            cvec[h] = s0; cvec[4 + h] = s1; cvec[8 + h] = d0; cvec[12 + h] = d1;
        }
    }
}

// layer-1 aggregation via rank-2 trick: thread per dst node, gather only x[src]
// (8B/edge, L2-resident). Edge loop unrolled x4 for MLP.
__global__ void k_agg1s(const float* __restrict__ x, const int* __restrict__ offs,
                        const int* __restrict__ ssrc, const float* __restrict__ cvec,
                        int N, float4* Sa, float4* Sb, float4* Sc){
    int n = blockIdx.x * blockDim.x + threadIdx.x;
    if (n >= N) return;
    float4 cs0 = ((const float4*)cvec)[0];
    float4 cs1 = ((const float4*)cvec)[1];
    float4 cd0 = ((const float4*)cvec)[2];
    float4 cd1 = ((const float4*)cvec)[3];
    float c0[4] = {cs0.x, cs0.y, cs0.z, cs0.w};
    float c1[4] = {cs1.x, cs1.y, cs1.z, cs1.w};
    float2 xn = ((const float2*)x)[n];
    float ad[4] = {xn.x*cd0.x + xn.y*cd1.x, xn.x*cd0.y + xn.y*cd1.y,
                   xn.x*cd0.z + xn.y*cd1.z, xn.x*cd0.w + xn.y*cd1.w};
    float A0[4] = {0,0,0,0}, A1[4] = {0,0,0,0}, D[4] = {0,0,0,0};
    int beg = offs[n], end = offs[n + 1];
    int j = beg;
    for (; j + 4 <= end; j += 4){
        int s0 = ssrc[j], s1 = ssrc[j+1], s2 = ssrc[j+2], s3 = ssrc[j+3];
        float2 xa = ((const float2*)x)[s0];
        float2 xb = ((const float2*)x)[s1];
        float2 xc = ((const float2*)x)[s2];
        float2 xd = ((const float2*)x)[s3];
#pragma unroll
        for (int h = 0; h < HEADS; h++){
            float wa = __expf(lrelu(xa.x * c0[h] + xa.y * c1[h] + ad[h]));
            float wb = __expf(lrelu(xb.x * c0[h] + xb.y * c1[h] + ad[h]));
            float wc = __expf(lrelu(xc.x * c0[h] + xc.y * c1[h] + ad[h]));
            float wd = __expf(lrelu(xd.x * c0[h] + xd.y * c1[h] + ad[h]));
            A0[h] += wa * xa.x + wb * xb.x + wc * xc.x + wd * xd.x;
            A1[h] += wa * xa.y + wb * xb.y + wc * xc.y + wd * xd.y;
            D[h]  += wa + wb + wc + wd;
        }
    }
    for (; j < end; j++){
        int s = ssrc[j];
        float2 xs = ((const float2*)x)[s];
#pragma unroll
        for (int h = 0; h < HEADS; h++){
            float e = xs.x * c0[h] + xs.y * c1[h] + ad[h];
            float w = __expf(lrelu(e));
            A0[h] += w * xs.x;
            A1[h] += w * xs.y;
            D[h]  += w;
        }
    }
    Sa[n] = make_float4(A0[0], A0[1], A0[2], A0[3]);
    Sb[n] = make_float4(A1[0], A1[1], A1[2], A1[3]);
    Sc[n] = make_float4(D[0],  D[1],  D[2],  D[3]);
}

// Fused: h1 row computed in-register from 12 scalars, GEMM vs W2 (W2 in VGPRs,
// 4-wave k-split), LDS broadcast of h, LDS partial reduce, attention dots.
__global__ void __launch_bounds__(256)
k_l2fused(const float* __restrict__ Saf, const float* __restrict__ Sbf,
          const float* __restrict__ Scf, const float* __restrict__ W1,
          const float* __restrict__ b1, const float* __restrict__ W2,
          const float* __restrict__ as2, const float* __restrict__ ad2,
          int N, float* __restrict__ xh2, float* __restrict__ asrc,
          float* __restrict__ adst){
    __shared__ float hS[NB][256];
    __shared__ float partS[4][NB][64];
    int lane = threadIdx.x & 63, w = threadIdx.x >> 6;
    int kk = w * 64 + lane;
    float w2r[64];
#pragma unroll
    for (int j = 0; j < 64; j++) w2r[j] = W2[(w * 64 + j) * 64 + lane];
    float w10 = W1[kk], w11 = W1[256 + kk], b1k = b1[kk];
    float asw = as2[lane], adw = ad2[lane];

    int nbatches = (N + NB - 1) / NB;
    for (int b = blockIdx.x; b < nbatches; b += gridDim.x){
        int n0 = b * NB;
#pragma unroll
        for (int m = 0; m < NB; m++){
            int n = n0 + m;
            if (n < N){
                float A0 = Saf[n * 4 + w], A1 = Sbf[n * 4 + w], Dv = Scf[n * 4 + w];
                float u = (A0 * w10 + A1 * w11) / Dv + b1k;
                hS[m][kk] = elu_(u);
            }
        }
        __syncthreads();
#pragma unroll
        for (int m = 0; m < NB; m++){
            float acc = 0.f;
            const float4* hp = (const float4*)&hS[m][w * 64];
#pragma unroll
            for (int q = 0; q < 16; q++){
                float4 hv = hp[q];
                acc += hv.x * w2r[4*q] + hv.y * w2r[4*q+1]
                     + hv.z * w2r[4*q+2] + hv.w * w2r[4*q+3];
            }
            partS[w][m][lane] = acc;
        }
        __syncthreads();
        for (int m = w; m < NB; m += 4){
            int n = n0 + m;
            if (n < N){
                float acc = partS[0][m][lane] + partS[1][m][lane]
                          + partS[2][m][lane] + partS[3][m][lane];
                xh2[(size_t)n * 64 + lane] = acc;
                float ps = acc * asw, pd = acc * adw;
#pragma unroll
                for (int off = 32; off; off >>= 1){
                    ps += __shfl_xor(ps, off, 64);
                    pd += __shfl_xor(pd, off, 64);
                }
                if (lane == 0){ asrc[n] = ps; adst[n] = pd; }
            }
        }
        __syncthreads();
    }
}

// layer-2 aggregation fused with global mean pool. Edge loop unrolled x4.
__global__ void k_agg2p(const float* __restrict__ xh2, const float* __restrict__ asrc,
                        const float* __restrict__ adst, const int* __restrict__ offs,
                        const int* __restrict__ ssrc, const float* __restrict__ b2,
                        const int* __restrict__ batch, int N,
                        float* sums, int* counts){
    int lane = threadIdx.x & 63, wv = threadIdx.x >> 6;  // 4 waves/block
    int wid = blockIdx.x * 4 + wv;
    int nw = gridDim.x * 4;
    int chunk = (N + nw - 1) / nw;
    int beg = wid * chunk, end = min(beg + chunk, N);
    if (beg >= end) return;
    float b2l = b2[lane];
    float pacc = 0.f; int pcnt = 0; int cur = batch[beg];
    for (int n = beg; n < end; n++){
        float ad = adst[n];
        float acc = 0.f, den = 0.f;
        int e0 = offs[n], e1 = offs[n + 1];
        int j = e0;
        for (; j + 4 <= e1; j += 4){
            int s0 = ssrc[j], s1 = ssrc[j+1], s2 = ssrc[j+2], s3 = ssrc[j+3];
            float a0 = asrc[s0], a1 = asrc[s1], a2 = asrc[s2], a3 = asrc[s3];
            float r0 = xh2[(size_t)s0 * 64 + lane];
            float r1 = xh2[(size_t)s1 * 64 + lane];
            float r2 = xh2[(size_t)s2 * 64 + lane];
            float r3 = xh2[(size_t)s3 * 64 + lane];
            float w0 = __expf(lrelu(a0 + ad));
            float w1 = __expf(lrelu(a1 + ad));
            float w2 = __expf(lrelu(a2 + ad));
            float w3 = __expf(lrelu(a3 + ad));
            acc += w0 * r0 + w1 * r1 + w2 * r2 + w3 * r3;
            den += w0 + w1 + w2 + w3;
        }
        for (; j < e1; j++){
            int s = ssrc[j];
            float wgt = __expf(lrelu(asrc[s] + ad));
            acc += wgt * xh2[(size_t)s * 64 + lane];
            den += wgt;
        }
        float h2v = elu_(acc / den + b2l);
        int g = batch[n];
        if (g != cur){
            atomicAdd(&sums[cur * HID + lane], pacc);
            if (lane == 0) atomicAdd(&counts[cur], pcnt);
            pacc = 0.f; pcnt = 0; cur = g;
        }
        pacc += h2v; pcnt++;
    }
    atomicAdd(&sums[cur * HID + lane], pacc);
    if (lane == 0) atomicAdd(&counts[cur], pcnt);
}

__global__ void k_final(const float* __restrict__ sums, const int* __restrict__ counts,
                        const float* __restrict__ Wl, const float* __restrict__ bl,
                        float* out){
    int t = threadIdx.x;
    if (t >= GR * 2) return;
    int g = t >> 1, task = t & 1;
    float c = (float)max(counts[g], 1);
    float acc = 0.f;
#pragma unroll
    for (int k = 0; k < HID; k++)
        acc += (sums[g * HID + k] / c) * Wl[k * 2 + task];
    out[t] = acc + bl[task];
}

extern "C" void kernel_launch(void* const* d_in, const int* in_sizes, int n_in,
                              void* d_out, int out_size, void* d_ws, size_t ws_size,
                              hipStream_t stream) {
    const float* x    = (const float*)d_in[0];
    const int*   ei   = (const int*)  d_in[1];
    const int*   batch= (const int*)  d_in[2];
    const float* W1   = (const float*)d_in[3];
    const float* as1  = (const float*)d_in[4];
    const float* ad1  = (const float*)d_in[5];
    const float* b1   = (const float*)d_in[6];
    const float* W2   = (const float*)d_in[7];
    const float* as2  = (const float*)d_in[8];
    const float* ad2  = (const float*)d_in[9];
    const float* b2   = (const float*)d_in[10];
    const float* Wl   = (const float*)d_in[11];
    const float* bl   = (const float*)d_in[12];
    float* out = (float*)d_out;

    int N  = in_sizes[0] / 2;
    int E  = in_sizes[1] / 2;
    int Et = E + N;
    const int* srcp = ei;
    const int* dstp = ei + E;

    char* p = (char*)d_ws;
    auto alloc = [&](size_t bytes)->char* {
        char* r = p; p += (bytes + 255) & ~(size_t)255; return r;
    };
    int*    deg    = (int*)   alloc((size_t)N * 4);
    int*    offs   = (int*)   alloc((size_t)(N + 1) * 4);
    int*    bsum   = (int*)   alloc(1024 * 4);
    int*    bcnt   = (int*)   alloc(NBKT_MAX * 4);
    int*    bbase  = (int*)   alloc(NBKT_MAX * 4);
    int*    bcursor= (int*)   alloc(NBKT_MAX * 4);
    int*    ssrc   = (int*)   alloc((size_t)Et * 4);
    unsigned long long* tmp = (unsigned long long*)alloc((size_t)E * 8);
    float*  cvec   = (float*) alloc(16 * 4);
    float4* Sa     = (float4*)alloc((size_t)N * 16);
    float4* Sb     = (float4*)alloc((size_t)N * 16);
    float4* Sc     = (float4*)alloc((size_t)N * 16);
    float*  asrc2  = (float*) alloc((size_t)N * 4);
    float*  adst2  = (float*) alloc((size_t)N * 4);
    float*  sums   = (float*) alloc((size_t)GR * HID * 4);
    int*    counts = (int*)   alloc((size_t)GR * 4);
    float*  xh2    = (float*) alloc((size_t)N * 64 * 4);

    int nb1024 = (N + 1023) / 1024;
    int nbkt   = (N + 255) >> BK_SH;

    k_init <<<(N + 255) / 256, 256, 0, stream>>>(deg, sums, counts, bcnt, N);
    k_hist2<<<1024, 256, 0, stream>>>(dstp, E, deg, bcnt);
    k_scan1<<<nb1024, 1024, 0, stream>>>(deg, N, offs, bsum);
    k_scan2<<<1, 1024, 0, stream>>>(bsum, nb1024);
    k_scan3<<<nb1024, 1024, 0, stream>>>(offs, bsum, N, Et);
    k_bscan<<<1, NBKT_MAX, 0, stream>>>(bcnt, bbase, bcursor);
    k_part <<<(E + PART_T - 1) / PART_T, 256, 0, stream>>>(srcp, dstp, E, bcursor, tmp);
    k_csr  <<<nbkt, 256, 0, stream>>>(tmp, bbase, bcnt, offs, N, ssrc);

    k_const<<<1, 64, 0, stream>>>(W1, as1, ad1, cvec);
    k_agg1s<<<(N + 255) / 256, 256, 0, stream>>>(x, offs, ssrc, cvec, N, Sa, Sb, Sc);
    k_l2fused<<<2048, 256, 0, stream>>>((const float*)Sa, (const float*)Sb,
                                        (const float*)Sc, W1, b1, W2, as2, ad2,
                                        N, xh2, asrc2, adst2);
    k_agg2p<<<2048, 256, 0, stream>>>(xh2, asrc2, adst2, offs, ssrc, b2,
                                      batch, N, sums, counts);
    k_final<<<1, 128, 0, stream>>>(sums, counts, Wl, bl, out);
}